// Round 1
// baseline (455.908 us; speedup 1.0000x reference)
//
#include <hip/hip_runtime.h>
#include <cstdint>
#include <cstddef>

// Problem constants (from reference): B=256, C=1, NMAX=256 -> N=65536 nodes,
// E = N*16 = 1048576 edges, EMB=HID=128, decode K = NMAX = 256.
#define NN   65536
#define NE   1048576
#define FD   128
#define KDEC 256
#define NGRAPH 256
#define ROWS_PER_G 256

// ---------------- CSR build: histogram, scan, scatter ----------------

__global__ __launch_bounds__(256) void k_hist(const int* __restrict__ edges,
                                              int* __restrict__ hist) {
  int i = blockIdx.x * 256 + threadIdx.x;
  if (i < NE) atomicAdd(&hist[edges[2 * i + 1]], 1);
}

__global__ __launch_bounds__(256) void k_blocksum(const int* __restrict__ hist,
                                                  int* __restrict__ bsum) {
  __shared__ int s[256];
  int t = threadIdx.x;
  s[t] = hist[blockIdx.x * 256 + t];
  __syncthreads();
  for (int st = 128; st > 0; st >>= 1) {
    if (t < st) s[t] += s[t + st];
    __syncthreads();
  }
  if (t == 0) bsum[blockIdx.x] = s[0];
}

// exclusive scan of 256 block sums, in place (single block)
__global__ __launch_bounds__(256) void k_scanb(int* __restrict__ bsum) {
  __shared__ int s[256];
  int t = threadIdx.x;
  int v = bsum[t];
  s[t] = v;
  __syncthreads();
  for (int off = 1; off < 256; off <<= 1) {
    int add = (t >= off) ? s[t - off] : 0;
    __syncthreads();
    s[t] += add;
    __syncthreads();
  }
  bsum[t] = s[t] - v;  // exclusive
}

__global__ __launch_bounds__(256) void k_scanfinal(const int* __restrict__ hist,
                                                   const int* __restrict__ bsum,
                                                   int* __restrict__ offs) {
  __shared__ int s[256];
  int t = threadIdx.x, b = blockIdx.x;
  int v = hist[b * 256 + t];
  s[t] = v;
  __syncthreads();
  for (int off = 1; off < 256; off <<= 1) {
    int add = (t >= off) ? s[t - off] : 0;
    __syncthreads();
    s[t] += add;
    __syncthreads();
  }
  offs[b * 256 + t] = bsum[b] + s[t] - v;  // exclusive global offsets
}

__global__ __launch_bounds__(256) void k_dinv(const int* __restrict__ hist,
                                              float* __restrict__ dinv) {
  int i = blockIdx.x * 256 + threadIdx.x;
  if (i < NN) dinv[i] = rsqrtf((float)(hist[i] + 1));
}

__global__ __launch_bounds__(256) void k_scatter(const int* __restrict__ edges,
                                                 const int* __restrict__ offs,
                                                 int* __restrict__ cnt,
                                                 int* __restrict__ ssrc) {
  int i = blockIdx.x * 256 + threadIdx.x;
  if (i < NE) {
    int s = edges[2 * i];
    int d = edges[2 * i + 1];
    int pos = offs[d] + atomicAdd(&cnt[d], 1);
    ssrc[pos] = s;
  }
}

// ---------------- fp32 tiled GEMM: Y[M,128] = X[M,K] @ W[K,128] (+bias) ----------------
// BM=64, BN=128 (full), BK=32; 256 threads; each thread 4x8 outputs.

__global__ __launch_bounds__(256) void k_gemm(const float* __restrict__ X,
                                              const float* __restrict__ W,
                                              const float* __restrict__ bias,
                                              float* __restrict__ Y, int K) {
  __shared__ float As[32][68];   // [kk][row], pad 68 -> 272B rows (16B aligned)
  __shared__ float Bs[32][132];  // [kk][col], pad 132 -> 528B rows (16B aligned)

  const int t = threadIdx.x;
  const int bm = blockIdx.x * 64;
  const int tx = t & 15;       // 16 col groups
  const int ty = t >> 4;       // 16 row groups
  const int r0 = ty * 4;
  const int c0 = tx * 8;
  const int lrow = t >> 2;         // 0..63
  const int lcol = (t & 3) * 8;    // 0,8,16,24

  float acc[4][8];
#pragma unroll
  for (int i = 0; i < 4; i++)
#pragma unroll
    for (int j = 0; j < 8; j++) acc[i][j] = 0.f;

  const float* xp0 = X + (size_t)(bm + lrow) * K + lcol;

  for (int k0 = 0; k0 < K; k0 += 32) {
    // stage X tile (64x32), transposed into As[kk][row]
    float4 xa = *(const float4*)(xp0 + k0);
    float4 xb = *(const float4*)(xp0 + k0 + 4);
    As[lcol + 0][lrow] = xa.x;
    As[lcol + 1][lrow] = xa.y;
    As[lcol + 2][lrow] = xa.z;
    As[lcol + 3][lrow] = xa.w;
    As[lcol + 4][lrow] = xb.x;
    As[lcol + 5][lrow] = xb.y;
    As[lcol + 6][lrow] = xb.z;
    As[lcol + 7][lrow] = xb.w;
    // stage W tile (32x128)
#pragma unroll
    for (int j = 0; j < 4; j++) {
      int e = j * 1024 + t * 4;
      int wr = e >> 7;
      int wc = e & 127;
      *(float4*)&Bs[wr][wc] = *(const float4*)(W + (size_t)(k0 + wr) * FD + wc);
    }
    __syncthreads();

#pragma unroll
    for (int kk = 0; kk < 32; kk++) {
      float4 av = *(const float4*)&As[kk][r0];
      float4 b0 = *(const float4*)&Bs[kk][c0];
      float4 b1 = *(const float4*)&Bs[kk][c0 + 4];
      float a[4] = {av.x, av.y, av.z, av.w};
      float b[8] = {b0.x, b0.y, b0.z, b0.w, b1.x, b1.y, b1.z, b1.w};
#pragma unroll
      for (int i = 0; i < 4; i++)
#pragma unroll
        for (int j = 0; j < 8; j++) acc[i][j] = fmaf(a[i], b[j], acc[i][j]);
    }
    __syncthreads();
  }

  float bv[8];
#pragma unroll
  for (int j = 0; j < 8; j++) bv[j] = bias ? bias[c0 + j] : 0.f;

#pragma unroll
  for (int i = 0; i < 4; i++) {
    float4* yp = (float4*)(Y + (size_t)(bm + r0 + i) * FD + c0);
    yp[0] = make_float4(acc[i][0] + bv[0], acc[i][1] + bv[1],
                        acc[i][2] + bv[2], acc[i][3] + bv[3]);
    yp[1] = make_float4(acc[i][4] + bv[4], acc[i][5] + bv[5],
                        acc[i][6] + bv[6], acc[i][7] + bv[7]);
  }
}

// ---------------- GCN aggregation (atomic-free, CSR) ----------------
// out[d] = relu( sum_{e: dst=d} dinv[src]*dinv[d]*h[src] + dinv[d]^2*h[d] + b )
// one wave (64 lanes) per dst node; lane owns dims 2l, 2l+1.

__global__ __launch_bounds__(256) void k_agg(const float* __restrict__ h,
                                             const int* __restrict__ ssrc,
                                             const int* __restrict__ offs,
                                             const int* __restrict__ hist,
                                             const float* __restrict__ dinv,
                                             const float* __restrict__ bias,
                                             float* __restrict__ out) {
  int w = (blockIdx.x * 256 + threadIdx.x) >> 6;  // node id
  int lane = threadIdx.x & 63;
  if (w >= NN) return;

  int start = offs[w];
  int cnt = hist[w];
  float dv = dinv[w];

  float ax = 0.f, ay = 0.f;
  int i = 0;
  // 2-wide unroll for load-level parallelism
  for (; i + 1 < cnt; i += 2) {
    int s0 = ssrc[start + i];
    int s1 = ssrc[start + i + 1];
    float c0 = dinv[s0] * dv;
    float c1 = dinv[s1] * dv;
    float2 v0 = *(const float2*)(h + (size_t)s0 * FD + lane * 2);
    float2 v1 = *(const float2*)(h + (size_t)s1 * FD + lane * 2);
    ax = fmaf(c0, v0.x, ax);
    ay = fmaf(c0, v0.y, ay);
    ax = fmaf(c1, v1.x, ax);
    ay = fmaf(c1, v1.y, ay);
  }
  if (i < cnt) {
    int s0 = ssrc[start + i];
    float c0 = dinv[s0] * dv;
    float2 v0 = *(const float2*)(h + (size_t)s0 * FD + lane * 2);
    ax = fmaf(c0, v0.x, ax);
    ay = fmaf(c0, v0.y, ay);
  }

  float2 hd = *(const float2*)(h + (size_t)w * FD + lane * 2);
  float2 bb = *(const float2*)(bias + lane * 2);
  float dd = dv * dv;
  float ox = fmaxf(ax + hd.x * dd + bb.x, 0.f);
  float oy = fmaxf(ay + hd.y * dd + bb.y, 0.f);
  *(float2*)(out + (size_t)w * FD + lane * 2) = make_float2(ox, oy);
}

// ---------------- segment max pool (256 rows per graph) ----------------

__global__ __launch_bounds__(128) void k_segmax(const float* __restrict__ x,
                                                float* __restrict__ pooled) {
  int g = blockIdx.x, t = threadIdx.x;
  const float* p = x + (size_t)g * ROWS_PER_G * FD + t;
  float m = -INFINITY;
  for (int r = 0; r < ROWS_PER_G; r++) m = fmaxf(m, p[(size_t)r * FD]);
  pooled[g * FD + t] = m;
}

// ---------------- MLP head: out[g] = (relu(pooled@Wp1+bp1)) @ Wp2 + bp2 ----------------

__global__ __launch_bounds__(128) void k_mlp(const float* __restrict__ pooled,
                                             const float* __restrict__ Wp1,
                                             const float* __restrict__ bp1,
                                             const float* __restrict__ Wp2,
                                             const float* __restrict__ bp2,
                                             float* __restrict__ out) {
  __shared__ float row[128];
  __shared__ float red[128];
  int g = blockIdx.x, t = threadIdx.x;
  row[t] = pooled[g * FD + t];
  __syncthreads();
  float acc = bp1[t];
#pragma unroll 8
  for (int k = 0; k < 128; k++) acc = fmaf(row[k], Wp1[k * FD + t], acc);
  acc = fmaxf(acc, 0.f);
  red[t] = acc * Wp2[t];
  __syncthreads();
  for (int st = 64; st > 0; st >>= 1) {
    if (t < st) red[t] += red[t + st];
    __syncthreads();
  }
  if (t == 0) out[g] = red[0] + bp2[0];
}

// ---------------- launch ----------------

extern "C" void kernel_launch(void* const* d_in, const int* in_sizes, int n_in,
                              void* d_out, int out_size, void* d_ws, size_t ws_size,
                              hipStream_t stream) {
  (void)in_sizes; (void)n_in; (void)out_size; (void)ws_size;

  const float* adj  = (const float*)d_in[0];
  const int*   edges= (const int*)d_in[1];
  // d_in[2] = subgraph_idx (layout is known: graph g = rows [g*256,(g+1)*256))
  const float* Wdec = (const float*)d_in[3];
  const float* bdec = (const float*)d_in[4];
  const float* Wc1  = (const float*)d_in[5];
  const float* bc1  = (const float*)d_in[6];
  const float* Wc2  = (const float*)d_in[7];
  const float* bc2  = (const float*)d_in[8];
  const float* Wp1  = (const float*)d_in[9];
  const float* bp1  = (const float*)d_in[10];
  const float* Wp2  = (const float*)d_in[11];
  const float* bp2  = (const float*)d_in[12];
  float* out = (float*)d_out;

  char* ws = (char*)d_ws;
  size_t off = 0;
  auto alloc = [&](size_t bytes) -> void* {
    void* p = ws + off;
    off += (bytes + 255) & ~(size_t)255;
    return p;
  };
  float* bufA  = (float*)alloc((size_t)NN * FD * 4);  // 32 MB
  float* bufB  = (float*)alloc((size_t)NN * FD * 4);  // 32 MB
  int*   hist  = (int*)alloc((size_t)NN * 4);
  int*   offs  = (int*)alloc((size_t)NN * 4);
  int*   cnt   = (int*)alloc((size_t)NN * 4);
  int*   bsum  = (int*)alloc(256 * 4);
  int*   ssrc  = (int*)alloc((size_t)NE * 4);         // 4 MB
  float* dinv  = (float*)alloc((size_t)NN * 4);
  float* pooled= (float*)alloc((size_t)NGRAPH * FD * 4);

  hipMemsetAsync(hist, 0, (size_t)NN * 4, stream);
  hipMemsetAsync(cnt, 0, (size_t)NN * 4, stream);

  // CSR build (shared by both GCN layers)
  k_hist<<<NE / 256, 256, 0, stream>>>(edges, hist);
  k_blocksum<<<256, 256, 0, stream>>>(hist, bsum);
  k_scanb<<<1, 256, 0, stream>>>(bsum);
  k_scanfinal<<<256, 256, 0, stream>>>(hist, bsum, offs);
  k_dinv<<<NN / 256, 256, 0, stream>>>(hist, dinv);
  k_scatter<<<NE / 256, 256, 0, stream>>>(edges, offs, cnt, ssrc);

  // x0 = adj @ Wdec + bdec
  k_gemm<<<NN / 64, 256, 0, stream>>>(adj, Wdec, bdec, bufA, KDEC);

  // layer 1: h = x0 @ Wc1 ; x1 = relu(agg(h) + h*dinv^2 + bc1)
  k_gemm<<<NN / 64, 256, 0, stream>>>(bufA, Wc1, nullptr, bufB, FD);
  k_agg<<<NN / 4, 256, 0, stream>>>(bufB, ssrc, offs, hist, dinv, bc1, bufA);

  // layer 2
  k_gemm<<<NN / 64, 256, 0, stream>>>(bufA, Wc2, nullptr, bufB, FD);
  k_agg<<<NN / 4, 256, 0, stream>>>(bufB, ssrc, offs, hist, dinv, bc2, bufA);

  // pool + MLP head
  k_segmax<<<NGRAPH, 128, 0, stream>>>(bufA, pooled);
  k_mlp<<<NGRAPH, 128, 0, stream>>>(pooled, Wp1, bp1, Wp2, bp2, out);
}

// Round 2
// 309.567 us; speedup vs baseline: 1.4727x; 1.4727x over previous
//
#include <hip/hip_runtime.h>
#include <cstdint>
#include <cstddef>

// Problem constants: B=256, C=1, NMAX=256 -> N=65536 nodes, E=N*16=1048576,
// EMB=HID=128, decode K = NMAX = 256.
#define NN   65536
#define NE   1048576
#define FD   128
#define KDEC 256
#define NGRAPH 256
#define ROWS_PER_G 256

typedef __attribute__((ext_vector_type(8))) short s16x8;
typedef __attribute__((ext_vector_type(4))) float f32x4;

__device__ __forceinline__ ushort f2bf(float x) {
  uint u = __float_as_uint(x);
  uint r = (u + 0x7fffu + ((u >> 16) & 1u)) >> 16;  // RNE
  return (ushort)r;
}
__device__ __forceinline__ float bf2f(ushort h) {
  return __uint_as_float(((uint)h) << 16);
}

// ---------------- CSR build: histogram, scan, scatter ----------------

__global__ __launch_bounds__(256) void k_hist(const int* __restrict__ edges,
                                              int* __restrict__ hist) {
  int i = blockIdx.x * 256 + threadIdx.x;
  if (i < NE) atomicAdd(&hist[edges[2 * i + 1]], 1);
}

__global__ __launch_bounds__(256) void k_blocksum(const int* __restrict__ hist,
                                                  int* __restrict__ bsum) {
  __shared__ int s[256];
  int t = threadIdx.x;
  s[t] = hist[blockIdx.x * 256 + t];
  __syncthreads();
  for (int st = 128; st > 0; st >>= 1) {
    if (t < st) s[t] += s[t + st];
    __syncthreads();
  }
  if (t == 0) bsum[blockIdx.x] = s[0];
}

__global__ __launch_bounds__(256) void k_scanb(int* __restrict__ bsum) {
  __shared__ int s[256];
  int t = threadIdx.x;
  int v = bsum[t];
  s[t] = v;
  __syncthreads();
  for (int off = 1; off < 256; off <<= 1) {
    int add = (t >= off) ? s[t - off] : 0;
    __syncthreads();
    s[t] += add;
    __syncthreads();
  }
  bsum[t] = s[t] - v;  // exclusive
}

__global__ __launch_bounds__(256) void k_scanfinal(const int* __restrict__ hist,
                                                   const int* __restrict__ bsum,
                                                   int* __restrict__ offs) {
  __shared__ int s[256];
  int t = threadIdx.x, b = blockIdx.x;
  int v = hist[b * 256 + t];
  s[t] = v;
  __syncthreads();
  for (int off = 1; off < 256; off <<= 1) {
    int add = (t >= off) ? s[t - off] : 0;
    __syncthreads();
    s[t] += add;
    __syncthreads();
  }
  offs[b * 256 + t] = bsum[b] + s[t] - v;
}

__global__ __launch_bounds__(256) void k_dinv(const int* __restrict__ hist,
                                              float* __restrict__ dinv) {
  int i = blockIdx.x * 256 + threadIdx.x;
  if (i < NN) dinv[i] = rsqrtf((float)(hist[i] + 1));
}

// scatter: CSR-ordered packed {src, coef}
__global__ __launch_bounds__(256) void k_scatter(const int* __restrict__ edges,
                                                 const int* __restrict__ offs,
                                                 int* __restrict__ cnt,
                                                 const float* __restrict__ dinv,
                                                 int2* __restrict__ ec) {
  int i = blockIdx.x * 256 + threadIdx.x;
  if (i < NE) {
    int s = edges[2 * i];
    int d = edges[2 * i + 1];
    int pos = offs[d] + atomicAdd(&cnt[d], 1);
    ec[pos] = make_int2(s, __float_as_int(dinv[s] * dinv[d]));
  }
}

// ---------------- W pre-fragmentation (split bf16, fragment-major) ----------------
// Layout: index(k,c) = ((k/32)*8 + c/16)*64*8 + ((c&15) + 16*((k&31)>>3))*8 + (k&7)

__global__ __launch_bounds__(256) void k_prepw(const float* __restrict__ W,
                                               ushort* __restrict__ Whi,
                                               ushort* __restrict__ Wlo, int K) {
  int i = blockIdx.x * 256 + threadIdx.x;
  if (i >= K * FD) return;
  int k = i >> 7, c = i & 127;
  float w = W[i];
  ushort h = f2bf(w);
  ushort lo = f2bf(w - bf2f(h));
  size_t dst = ((size_t)((k >> 5) * 8 + (c >> 4)) * 64 +
                (size_t)((c & 15) + 16 * ((k & 31) >> 3))) * 8 + (k & 7);
  Whi[dst] = h;
  Wlo[dst] = lo;
}

// ---------------- split-bf16 MFMA GEMM: Y[M,128] = X[M,K] @ W[K,128] (+bias) ----------------
// 256 threads = 4 waves; BM=128 (wave w owns rows [w*32, w*32+32) = 2 m-frags);
// no LDS: A from global fp32 (split in regs), B from pre-fragmented planes (L2-hot).

template <bool OUTBF16>
__global__ __launch_bounds__(256) void k_gemm(const float* __restrict__ X,
                                              const ushort* __restrict__ Whi,
                                              const ushort* __restrict__ Wlo,
                                              const float* __restrict__ bias,
                                              void* __restrict__ Yv, int K) {
  const int t = threadIdx.x;
  const int w = t >> 6;
  const int l = t & 63;
  const int lr = l & 15;   // row-in-frag (A) / col-in-frag (B,C)
  const int kg = l >> 4;   // k-group 0..3
  const int r0 = blockIdx.x * 128 + w * 32;

  f32x4 acc[2][8];
#pragma unroll
  for (int mb = 0; mb < 2; mb++)
#pragma unroll
    for (int nb = 0; nb < 8; nb++) acc[mb][nb] = (f32x4)0.f;

  for (int ks = 0; ks < K; ks += 32) {
    // A fragments: 8 consecutive fp32 per lane, split hi/lo
    s16x8 ah[2], al[2];
#pragma unroll
    for (int mb = 0; mb < 2; mb++) {
      const float* xp = X + (size_t)(r0 + mb * 16 + lr) * K + ks + kg * 8;
      f32x4 x0 = *(const f32x4*)xp;
      f32x4 x1 = *(const f32x4*)(xp + 4);
      float xv[8] = {x0.x, x0.y, x0.z, x0.w, x1.x, x1.y, x1.z, x1.w};
      union { ushort u[8]; s16x8 v; } H, L;
#pragma unroll
      for (int e = 0; e < 8; e++) {
        ushort h = f2bf(xv[e]);
        H.u[e] = h;
        L.u[e] = f2bf(xv[e] - bf2f(h));
      }
      ah[mb] = H.v;
      al[mb] = L.v;
    }
    // B fragments (pre-fragmented planes)
    const size_t bbase = (size_t)(ks >> 5) * 4096 + (size_t)l * 8;
    s16x8 bh[8], bl[8];
#pragma unroll
    for (int nb = 0; nb < 8; nb++) {
      bh[nb] = *(const s16x8*)(Whi + bbase + nb * 512);
      bl[nb] = *(const s16x8*)(Wlo + bbase + nb * 512);
    }
    // 3-pass split MFMA
#pragma unroll
    for (int mb = 0; mb < 2; mb++)
#pragma unroll
      for (int nb = 0; nb < 8; nb++) {
        acc[mb][nb] = __builtin_amdgcn_mfma_f32_16x16x32_bf16(ah[mb], bh[nb], acc[mb][nb], 0, 0, 0);
        acc[mb][nb] = __builtin_amdgcn_mfma_f32_16x16x32_bf16(ah[mb], bl[nb], acc[mb][nb], 0, 0, 0);
        acc[mb][nb] = __builtin_amdgcn_mfma_f32_16x16x32_bf16(al[mb], bh[nb], acc[mb][nb], 0, 0, 0);
      }
  }

  // epilogue: C/D col = lr, row = kg*4 + reg
#pragma unroll
  for (int nb = 0; nb < 8; nb++) {
    int col = nb * 16 + lr;
    float bv = bias ? bias[col] : 0.f;
#pragma unroll
    for (int mb = 0; mb < 2; mb++) {
#pragma unroll
      for (int r = 0; r < 4; r++) {
        size_t row = (size_t)(r0 + mb * 16 + kg * 4 + r);
        float v = acc[mb][nb][r] + bv;
        if (OUTBF16)
          ((ushort*)Yv)[row * FD + col] = f2bf(v);
        else
          ((float*)Yv)[row * FD + col] = v;
      }
    }
  }
}

// ---------------- GCN aggregation: bf16 gather table, atomic-free CSR ----------------
// one wave per dst node; lane l: half = l>>5 (edge parity), dims 4*(l&31)..+3.
// out[d] = relu( sum coef*h[src] + dinv[d]^2*h[d] + b )

__global__ __launch_bounds__(256) void k_agg(const ushort* __restrict__ h16,
                                             const int2* __restrict__ ec,
                                             const int* __restrict__ offs,
                                             const int* __restrict__ hist,
                                             const float* __restrict__ dinv,
                                             const float* __restrict__ bias,
                                             float* __restrict__ out) {
  int w = (blockIdx.x * 256 + threadIdx.x) >> 6;
  int l = threadIdx.x & 63;
  if (w >= NN) return;

  int start = offs[w];
  int cnt = hist[w];
  int half = l >> 5;
  int dl = (l & 31) * 4;

  float a0 = 0.f, a1 = 0.f, a2 = 0.f, a3 = 0.f;
  int i = half;
  for (; i + 2 < cnt; i += 4) {
    int2 e0 = ec[start + i];
    int2 e1 = ec[start + i + 2];
    ushort4 v0 = *(const ushort4*)(h16 + ((size_t)e0.x << 7) + dl);
    ushort4 v1 = *(const ushort4*)(h16 + ((size_t)e1.x << 7) + dl);
    float c0 = __int_as_float(e0.y);
    float c1 = __int_as_float(e1.y);
    a0 = fmaf(c0, bf2f(v0.x), a0);
    a1 = fmaf(c0, bf2f(v0.y), a1);
    a2 = fmaf(c0, bf2f(v0.z), a2);
    a3 = fmaf(c0, bf2f(v0.w), a3);
    a0 = fmaf(c1, bf2f(v1.x), a0);
    a1 = fmaf(c1, bf2f(v1.y), a1);
    a2 = fmaf(c1, bf2f(v1.z), a2);
    a3 = fmaf(c1, bf2f(v1.w), a3);
  }
  if (i < cnt) {
    int2 e0 = ec[start + i];
    ushort4 v0 = *(const ushort4*)(h16 + ((size_t)e0.x << 7) + dl);
    float c0 = __int_as_float(e0.y);
    a0 = fmaf(c0, bf2f(v0.x), a0);
    a1 = fmaf(c0, bf2f(v0.y), a1);
    a2 = fmaf(c0, bf2f(v0.z), a2);
    a3 = fmaf(c0, bf2f(v0.w), a3);
  }

  a0 += __shfl_xor(a0, 32);
  a1 += __shfl_xor(a1, 32);
  a2 += __shfl_xor(a2, 32);
  a3 += __shfl_xor(a3, 32);

  if (l < 32) {
    float dv = dinv[w];
    float dd = dv * dv;
    ushort4 vs = *(const ushort4*)(h16 + ((size_t)w << 7) + dl);
    float4 bb = *(const float4*)(bias + dl);
    float4 o;
    o.x = fmaxf(a0 + bf2f(vs.x) * dd + bb.x, 0.f);
    o.y = fmaxf(a1 + bf2f(vs.y) * dd + bb.y, 0.f);
    o.z = fmaxf(a2 + bf2f(vs.z) * dd + bb.z, 0.f);
    o.w = fmaxf(a3 + bf2f(vs.w) * dd + bb.w, 0.f);
    *(float4*)(out + ((size_t)w << 7) + dl) = o;
  }
}

// ---------------- segment max pool ----------------

__global__ __launch_bounds__(128) void k_segmax(const float* __restrict__ x,
                                                float* __restrict__ pooled) {
  int g = blockIdx.x, t = threadIdx.x;
  const float* p = x + (size_t)g * ROWS_PER_G * FD + t;
  float m = -INFINITY;
  for (int r = 0; r < ROWS_PER_G; r++) m = fmaxf(m, p[(size_t)r * FD]);
  pooled[g * FD + t] = m;
}

// ---------------- MLP head ----------------

__global__ __launch_bounds__(128) void k_mlp(const float* __restrict__ pooled,
                                             const float* __restrict__ Wp1,
                                             const float* __restrict__ bp1,
                                             const float* __restrict__ Wp2,
                                             const float* __restrict__ bp2,
                                             float* __restrict__ out) {
  __shared__ float row[128];
  __shared__ float red[128];
  int g = blockIdx.x, t = threadIdx.x;
  row[t] = pooled[g * FD + t];
  __syncthreads();
  float acc = bp1[t];
#pragma unroll 8
  for (int k = 0; k < 128; k++) acc = fmaf(row[k], Wp1[k * FD + t], acc);
  acc = fmaxf(acc, 0.f);
  red[t] = acc * Wp2[t];
  __syncthreads();
  for (int st = 64; st > 0; st >>= 1) {
    if (t < st) red[t] += red[t + st];
    __syncthreads();
  }
  if (t == 0) out[g] = red[0] + bp2[0];
}

// ---------------- launch ----------------

extern "C" void kernel_launch(void* const* d_in, const int* in_sizes, int n_in,
                              void* d_out, int out_size, void* d_ws, size_t ws_size,
                              hipStream_t stream) {
  (void)in_sizes; (void)n_in; (void)out_size; (void)ws_size;

  const float* adj  = (const float*)d_in[0];
  const int*   edges= (const int*)d_in[1];
  const float* Wdec = (const float*)d_in[3];
  const float* bdec = (const float*)d_in[4];
  const float* Wc1  = (const float*)d_in[5];
  const float* bc1  = (const float*)d_in[6];
  const float* Wc2  = (const float*)d_in[7];
  const float* bc2  = (const float*)d_in[8];
  const float* Wp1  = (const float*)d_in[9];
  const float* bp1  = (const float*)d_in[10];
  const float* Wp2  = (const float*)d_in[11];
  const float* bp2  = (const float*)d_in[12];
  float* out = (float*)d_out;

  char* ws = (char*)d_ws;
  size_t off = 0;
  auto alloc = [&](size_t bytes) -> void* {
    void* p = ws + off;
    off += (bytes + 255) & ~(size_t)255;
    return p;
  };
  float*  bufA = (float*)alloc((size_t)NN * FD * 4);   // 32 MB fp32 x-buffer
  ushort* bufH = (ushort*)alloc((size_t)NN * FD * 2);  // 16 MB bf16 h-table
  int*    hist = (int*)alloc((size_t)NN * 4);
  int*    offs = (int*)alloc((size_t)NN * 4);
  int*    cnt  = (int*)alloc((size_t)NN * 4);
  int*    bsum = (int*)alloc(256 * 4);
  int2*   ec   = (int2*)alloc((size_t)NE * 8);         // 8 MB packed {src,coef}
  float*  dinv = (float*)alloc((size_t)NN * 4);
  float*  pooled = (float*)alloc((size_t)NGRAPH * FD * 4);
  ushort* wdh = (ushort*)alloc((size_t)KDEC * FD * 2);
  ushort* wdl = (ushort*)alloc((size_t)KDEC * FD * 2);
  ushort* w1h = (ushort*)alloc((size_t)FD * FD * 2);
  ushort* w1l = (ushort*)alloc((size_t)FD * FD * 2);
  ushort* w2h = (ushort*)alloc((size_t)FD * FD * 2);
  ushort* w2l = (ushort*)alloc((size_t)FD * FD * 2);

  hipMemsetAsync(hist, 0, (size_t)NN * 4, stream);
  hipMemsetAsync(cnt, 0, (size_t)NN * 4, stream);

  // CSR build (shared by both GCN layers)
  k_hist<<<NE / 256, 256, 0, stream>>>(edges, hist);
  k_blocksum<<<256, 256, 0, stream>>>(hist, bsum);
  k_scanb<<<1, 256, 0, stream>>>(bsum);
  k_scanfinal<<<256, 256, 0, stream>>>(hist, bsum, offs);
  k_dinv<<<NN / 256, 256, 0, stream>>>(hist, dinv);
  k_scatter<<<NE / 256, 256, 0, stream>>>(edges, offs, cnt, dinv, ec);

  // W split+fragment (once; reused by all GEMM blocks)
  k_prepw<<<(KDEC * FD + 255) / 256, 256, 0, stream>>>(Wdec, wdh, wdl, KDEC);
  k_prepw<<<(FD * FD + 255) / 256, 256, 0, stream>>>(Wc1, w1h, w1l, FD);
  k_prepw<<<(FD * FD + 255) / 256, 256, 0, stream>>>(Wc2, w2h, w2l, FD);

  // x0 = adj @ Wdec + bdec  (fp32 out)
  k_gemm<false><<<NN / 128, 256, 0, stream>>>(adj, wdh, wdl, bdec, bufA, KDEC);

  // layer 1: h1 = x0 @ Wc1 (bf16 out) ; x1 = relu(agg(h1) + self + bc1)
  k_gemm<true><<<NN / 128, 256, 0, stream>>>(bufA, w1h, w1l, nullptr, bufH, FD);
  k_agg<<<NN / 4, 256, 0, stream>>>(bufH, ec, offs, hist, dinv, bc1, bufA);

  // layer 2
  k_gemm<true><<<NN / 128, 256, 0, stream>>>(bufA, w2h, w2l, nullptr, bufH, FD);
  k_agg<<<NN / 4, 256, 0, stream>>>(bufH, ec, offs, hist, dinv, bc2, bufA);

  // pool + MLP head
  k_segmax<<<NGRAPH, 128, 0, stream>>>(bufA, pooled);
  k_mlp<<<NGRAPH, 128, 0, stream>>>(pooled, Wp1, bp1, Wp2, bp2, out);
}